// Round 3
// baseline (847.719 us; speedup 1.0000x reference)
//
#include <hip/hip_runtime.h>

typedef __attribute__((ext_vector_type(8))) short short8;
typedef __attribute__((ext_vector_type(4))) float f32x4;

#define N_TOK 98
#define HD    32
#define NH    4
#define DIM   128
#define C3    384
#define NWIN  64
#define B_TOT 2048
#define MT    112                    // padded token count (7 x 16)
#define SCALE 0.17677669529663687f   // 1/sqrt(32)
#define CSHIFT 8.0f                  // uniform softmax shift (cancels in normalization)

// LDS layout (bytes):
//   sQ  [112][40]s @0     (8960), sK [112][40]s @8960 (8960)
//   sP  [112][136]s @0    (30464) -- aliases sQ/sK after QK barrier
//   sVT [32][136]s @30464 (8704)
//   sOh [112][40]s @39168 (8960)  -- per-head O, wave-private rows
#define SQK    40
#define SPS    136
#define SVS    136
#define SOH    40
#define K_OFF  8960
#define VT_OFF 30464
#define OH_OFF 39168
#define LDSZ   48128

#define BIAS_ELEMS (NH * MT * MT)          // 50176
#define WPERM_ELEMS (NH * 8 * 4 * 16 * 8)  // 16384
#define WPERM_BYTE_OFF 200704              // biasD bytes (fp32)

__device__ __forceinline__ short f2bf(float f) {       // RNE fp32->bf16
    unsigned u = __builtin_bit_cast(unsigned, f);
    u += 0x7fffu + ((u >> 16) & 1u);
    return (short)(u >> 16);
}

// ---------------------------------------------------------------------------
// prep: biasD[h][i][j] = rpb[rpi[i][j]*4 + h]  (padded 112x112)  and
//       wperm fragment-ordered bf16 W: wperm[(((h*8+nt)*4+q)*16+c)*8+k]
//         = W[nt*16+c][h*32+q*8+k]
// ---------------------------------------------------------------------------
__global__ void prep_kernel(const int* __restrict__ rpi,
                            const float* __restrict__ rpb,
                            const float* __restrict__ wmat,
                            float* __restrict__ biasD,
                            short* __restrict__ wperm) {
    int idx = blockIdx.x * 256 + threadIdx.x;
    if (idx < BIAS_ELEMS) {
        int j = idx % MT, rest = idx / MT;
        int i = rest % MT, h = rest / MT;
        float v = 0.f;
        if (i < N_TOK && j < N_TOK) v = rpb[rpi[i * N_TOK + j] * NH + h];
        biasD[idx] = v;
    } else if (idx < BIAS_ELEMS + WPERM_ELEMS) {
        int e = idx - BIAS_ELEMS;
        int k = e & 7, r2 = e >> 3;
        int c = r2 & 15; r2 >>= 4;
        int q = r2 & 3;  r2 >>= 2;
        int nt = r2 & 7; int h = r2 >> 3;
        wperm[e] = f2bf(wmat[(nt * 16 + c) * DIM + h * HD + q * 8 + k]);
    }
}

// ---------------------------------------------------------------------------
// Fused attention + projection: 1 block per window, 448 thr = 7 waves.
// Heads sequential; proj accumulated per head into registers (no phase C).
// ---------------------------------------------------------------------------
__global__ __launch_bounds__(448, 6) void fused_kernel(
    const float* __restrict__ x, const float* __restrict__ mask,
    const float* __restrict__ biasD, const short* __restrict__ wperm,
    const float* __restrict__ pbias, float* __restrict__ out)
{
    __shared__ __align__(16) char smem[LDSZ];
    short* sQ  = (short*)smem;                 // [112][40]
    short* sK  = (short*)(smem + K_OFF);       // [112][40]
    short* sP  = (short*)smem;                 // [112][136], aliases sQ/sK
    short* sVT = (short*)(smem + VT_OFF);      // [32][136]
    short* sOh = (short*)(smem + OH_OFF);      // [112][40]

    const int t = threadIdx.x;
    const int b = blockIdx.x;
    const int w = b & (NWIN - 1);
    const float* xb = x + (size_t)b * N_TOK * C3;

    const int lane = t & 63;
    const int c    = lane & 15, q = lane >> 4;
    const int m0   = (t >> 6) * 16;            // M-tile base, 0..96

    // persistent projection accumulators: rows m0+q*4+r, cols nt*16+c
    f32x4 pacc[8];
    #pragma unroll
    for (int nt = 0; nt < 8; ++nt) pacc[nt] = (f32x4){0.f, 0.f, 0.f, 0.f};

    // zero sVT token-pad columns once (j = 98..135)
    for (int e = t; e < HD * (SVS - N_TOK); e += 448) {
        int d = e / (SVS - N_TOK), j = N_TOK + e % (SVS - N_TOK);
        sVT[d * SVS + j] = 0;
    }

    for (int h = 0; h < NH; ++h) {
        // ---- stage Q (scaled), K as bf16 [token][d]; pad rows 98..111 = 0 ----
        for (int e = t; e < MT * 8; e += 448) {
            int row = e >> 3, d4 = (e & 7) << 2;
            unsigned long long qp = 0ull, kp = 0ull;
            if (row < N_TOK) {
                const float* p = xb + row * C3 + h * HD + d4;
                float4 qv = *(const float4*)p;
                float4 kv = *(const float4*)(p + DIM);
                qp =  (unsigned long long)(unsigned short)f2bf(qv.x * SCALE)
                   | ((unsigned long long)(unsigned short)f2bf(qv.y * SCALE) << 16)
                   | ((unsigned long long)(unsigned short)f2bf(qv.z * SCALE) << 32)
                   | ((unsigned long long)(unsigned short)f2bf(qv.w * SCALE) << 48);
                kp =  (unsigned long long)(unsigned short)f2bf(kv.x)
                   | ((unsigned long long)(unsigned short)f2bf(kv.y) << 16)
                   | ((unsigned long long)(unsigned short)f2bf(kv.z) << 32)
                   | ((unsigned long long)(unsigned short)f2bf(kv.w) << 48);
            }
            *(unsigned long long*)&sQ[row * SQK + d4] = qp;
            *(unsigned long long*)&sK[row * SQK + d4] = kp;
        }
        // ---- stage V transposed: sVT[d][j] ----
        for (int e = t; e < N_TOK * 8; e += 448) {
            int j = e >> 3, d4 = (e & 7) << 2;
            float4 vv = *(const float4*)(xb + j * C3 + 2 * DIM + h * HD + d4);
            sVT[(d4 + 0) * SVS + j] = f2bf(vv.x);
            sVT[(d4 + 1) * SVS + j] = f2bf(vv.y);
            sVT[(d4 + 2) * SVS + j] = f2bf(vv.z);
            sVT[(d4 + 3) * SVS + j] = f2bf(vv.w);
        }
        __syncthreads();   // staging done

        // ---- S = Q K^T : 7 MFMAs ----
        short8 afrag = *(const short8*)&sQ[(m0 + c) * SQK + q * 8];
        f32x4 acc[7];
        #pragma unroll
        for (int nt = 0; nt < 7; ++nt) {
            f32x4 z = {0.f, 0.f, 0.f, 0.f};
            short8 bfrag = *(const short8*)&sK[(nt * 16 + c) * SQK + q * 8];
            acc[nt] = __builtin_amdgcn_mfma_f32_16x16x32_bf16(afrag, bfrag, z, 0, 0, 0);
        }
        __syncthreads();   // all QK reads done; sP may overwrite sQ/sK

        // ---- bias + mask + shifted exp (no row max), write P immediately ----
        float sm[4] = {0.f, 0.f, 0.f, 0.f};
        #pragma unroll
        for (int nt = 0; nt < 7; ++nt) {
            int j = nt * 16 + c;
            #pragma unroll
            for (int r = 0; r < 4; ++r) {
                int i = m0 + q * 4 + r;
                float v = acc[nt][r] + biasD[(h * MT + i) * MT + j];
                if (j < N_TOK && i < N_TOK)
                    v += mask[((size_t)w * N_TOK + i) * N_TOK + j];
                float e = (j < N_TOK) ? __expf(v - CSHIFT) : 0.f;
                sm[r] += e;
                sP[i * SPS + j] = f2bf(e);
            }
        }
        // zero k-pad cols 112..127 of own rows
        #pragma unroll
        for (int kk = 0; kk < 4; ++kk)
            sP[(m0 + c) * SPS + 112 + q * 4 + kk] = 0;
        float inv[4];
        #pragma unroll
        for (int r = 0; r < 4; ++r) {
            float s = sm[r];
            s += __shfl_xor(s, 1);
            s += __shfl_xor(s, 2);
            s += __shfl_xor(s, 4);
            s += __shfl_xor(s, 8);
            inv[r] = 1.0f / s;   // normalization applied at sOh write
        }

        // ---- O_h = P V : 4 K-tiles x 2 N-tiles (own rows only) ----
        f32x4 oacc[2] = {{0.f,0.f,0.f,0.f}, {0.f,0.f,0.f,0.f}};
        #pragma unroll
        for (int kt = 0; kt < 4; ++kt) {
            short8 pa = *(const short8*)&sP[(m0 + c) * SPS + kt * 32 + q * 8];
            #pragma unroll
            for (int n2 = 0; n2 < 2; ++n2) {
                short8 vb = *(const short8*)&sVT[(n2 * 16 + c) * SVS + kt * 32 + q * 8];
                oacc[n2] = __builtin_amdgcn_mfma_f32_16x16x32_bf16(pa, vb, oacc[n2], 0, 0, 0);
            }
        }
        // ---- normalized O_h (bf16) into wave-private sOh rows ----
        #pragma unroll
        for (int n2 = 0; n2 < 2; ++n2)
            #pragma unroll
            for (int r = 0; r < 4; ++r)
                sOh[(m0 + q * 4 + r) * SOH + n2 * 16 + c] = f2bf(oacc[n2][r] * inv[r]);

        __syncthreads();   // sP/sVT reads done (restage ok); sOh visible

        // ---- proj accumulate: pacc[nt] += O_h @ W_h^T  (overlaps next stage) ----
        short8 pa2 = *(const short8*)&sOh[(m0 + c) * SOH + q * 8];
        #pragma unroll
        for (int nt = 0; nt < 8; ++nt) {
            short8 wb = *(const short8*)&wperm[(((h * 8 + nt) * 4 + q) * 16 + c) * 8];
            pacc[nt] = __builtin_amdgcn_mfma_f32_16x16x32_bf16(pa2, wb, pacc[nt], 0, 0, 0);
        }
    }

    // ---- epilogue: out = pacc + pbias ----
    #pragma unroll
    for (int nt = 0; nt < 8; ++nt) {
        float bc = pbias[nt * 16 + c];
        #pragma unroll
        for (int r = 0; r < 4; ++r) {
            int i = m0 + q * 4 + r;
            if (i < N_TOK)
                out[((size_t)b * N_TOK + i) * DIM + nt * 16 + c] = pacc[nt][r] + bc;
        }
    }
}

extern "C" void kernel_launch(void* const* d_in, const int* in_sizes, int n_in,
                              void* d_out, int out_size, void* d_ws, size_t ws_size,
                              hipStream_t stream) {
    const float* x    = (const float*)d_in[0];
    const int*   rpi  = (const int*)  d_in[1];
    const float* mask = (const float*)d_in[2];
    const float* rpb  = (const float*)d_in[3];
    const float* pw   = (const float*)d_in[4];
    const float* pb   = (const float*)d_in[5];
    float* out   = (float*)d_out;
    float* biasD = (float*)d_ws;                           // 200704 B
    short* wperm = (short*)((char*)d_ws + WPERM_BYTE_OFF); // 32768 B

    prep_kernel<<<(BIAS_ELEMS + WPERM_ELEMS + 255) / 256, 256, 0, stream>>>(
        rpi, rpb, pw, biasD, wperm);
    fused_kernel<<<B_TOT, 448, 0, stream>>>(x, mask, biasD, wperm, pb, out);
}

// Round 4
// 607.521 us; speedup vs baseline: 1.3954x; 1.3954x over previous
//
#include <hip/hip_runtime.h>

typedef __attribute__((ext_vector_type(8))) short short8;
typedef __attribute__((ext_vector_type(4))) float f32x4;

#define N_TOK 98
#define HD    32
#define NH    4
#define DIM   128
#define C3    384
#define NWIN  64
#define B_TOT 2048
#define MT    112                    // padded token count (7 x 16)
#define SCALE 0.17677669529663687f   // 1/sqrt(32)
#define CSHIFT 8.0f                  // uniform softmax shift (cancels in normalization)

// attn LDS layout (bytes):
//   sQ [112][40]s @0 (8960), sK [112][40]s @8960 (8960)
//   sP [112][136]s @0 (30464) -- aliases sQ/sK after QK barrier
//   sVT [32][136]s @30464 (8704)
#define SQK    40
#define SPS    136
#define SVS    136
#define K_OFF  8960
#define VT_OFF 30464
#define LDSZ   39168                 // 4 blocks/CU

#define BIAS_ELEMS (NH * MT * MT)          // 50176
#define WPERM_ELEMS (NH * 8 * 4 * 16 * 8)  // 16384
#define WPERM_BYTE_OFF 200704              // after biasD (fp32)
#define OBF_BYTE_OFF   233472              // after wperm; 16B aligned
#define OBF_BYTES ((size_t)B_TOT * N_TOK * DIM * 2)   // 51,380,224

__device__ __forceinline__ short f2bf(float f) {       // RNE fp32->bf16
    unsigned u = __builtin_bit_cast(unsigned, f);
    u += 0x7fffu + ((u >> 16) & 1u);
    return (short)(u >> 16);
}

// ---------------------------------------------------------------------------
// prep: biasD[h][i][j] = rpb[rpi[i][j]*4 + h]  (padded 112x112)  and
//       wperm fragment-ordered bf16 W: wperm[(((h*8+nt)*4+q)*16+c)*8+k]
//         = W[nt*16+c][h*32+q*8+k]
// ---------------------------------------------------------------------------
__global__ void prep_kernel(const int* __restrict__ rpi,
                            const float* __restrict__ rpb,
                            const float* __restrict__ wmat,
                            float* __restrict__ biasD,
                            short* __restrict__ wperm) {
    int idx = blockIdx.x * 256 + threadIdx.x;
    if (idx < BIAS_ELEMS) {
        int j = idx % MT, rest = idx / MT;
        int i = rest % MT, h = rest / MT;
        float v = 0.f;
        if (i < N_TOK && j < N_TOK) v = rpb[rpi[i * N_TOK + j] * NH + h];
        biasD[idx] = v;
    } else if (idx < BIAS_ELEMS + WPERM_ELEMS) {
        int e = idx - BIAS_ELEMS;
        int k = e & 7, r2 = e >> 3;
        int c = r2 & 15; r2 >>= 4;
        int q = r2 & 3;  r2 >>= 2;
        int nt = r2 & 7; int h = r2 >> 3;
        wperm[e] = f2bf(wmat[(nt * 16 + c) * DIM + h * HD + q * 8 + k]);
    }
}

// ---------------------------------------------------------------------------
// Attention: 1 block per (window,head), 448 thr = 7 waves = 7 M-tiles.
// bias+mask-CSHIFT folded into MFMA C-input; softmax = bare expf.
// Writes O bf16 to obf (if use_bf) else fp32 to out.
// ---------------------------------------------------------------------------
__global__ __launch_bounds__(448, 7) void attn_kernel(
    const float* __restrict__ x, const float* __restrict__ mask,
    const float* __restrict__ biasD, float* __restrict__ out,
    short* __restrict__ obf, const int use_bf)
{
    __shared__ __align__(16) char smem[LDSZ];
    short* sQ  = (short*)smem;                 // [112][40]
    short* sK  = (short*)(smem + K_OFF);       // [112][40]
    short* sP  = (short*)smem;                 // [112][136], aliases sQ/sK
    short* sVT = (short*)(smem + VT_OFF);      // [32][136]

    const int t  = threadIdx.x;
    const int bh = blockIdx.x;
    const int b  = bh >> 2, h = bh & 3;
    const int w  = b & (NWIN - 1);
    const float* xb = x + (size_t)b * N_TOK * C3;

    const int lane = t & 63;
    const int c    = lane & 15, q = lane >> 4;
    const int m0   = (t >> 6) * 16;

    // ---- stage Q (scaled), K as bf16 [token][d]; pad rows 98..111 = 0 ----
    for (int e = t; e < MT * 8; e += 448) {
        int row = e >> 3, d4 = (e & 7) << 2;
        unsigned long long qp = 0ull, kp = 0ull;
        if (row < N_TOK) {
            const float* p = xb + row * C3 + h * HD + d4;
            float4 qv = *(const float4*)p;
            float4 kv = *(const float4*)(p + DIM);
            qp =  (unsigned long long)(unsigned short)f2bf(qv.x * SCALE)
               | ((unsigned long long)(unsigned short)f2bf(qv.y * SCALE) << 16)
               | ((unsigned long long)(unsigned short)f2bf(qv.z * SCALE) << 32)
               | ((unsigned long long)(unsigned short)f2bf(qv.w * SCALE) << 48);
            kp =  (unsigned long long)(unsigned short)f2bf(kv.x)
               | ((unsigned long long)(unsigned short)f2bf(kv.y) << 16)
               | ((unsigned long long)(unsigned short)f2bf(kv.z) << 32)
               | ((unsigned long long)(unsigned short)f2bf(kv.w) << 48);
        }
        *(unsigned long long*)&sQ[row * SQK + d4] = qp;
        *(unsigned long long*)&sK[row * SQK + d4] = kp;
    }
    // ---- stage V transposed: sVT[d][j], zero pad j>=98 ----
    for (int e = t; e < N_TOK * 8; e += 448) {
        int j = e >> 3, d4 = (e & 7) << 2;
        float4 vv = *(const float4*)(xb + j * C3 + 2 * DIM + h * HD + d4);
        sVT[(d4 + 0) * SVS + j] = f2bf(vv.x);
        sVT[(d4 + 1) * SVS + j] = f2bf(vv.y);
        sVT[(d4 + 2) * SVS + j] = f2bf(vv.z);
        sVT[(d4 + 3) * SVS + j] = f2bf(vv.w);
    }
    for (int e = t; e < HD * (SVS - N_TOK); e += 448) {
        int d = e / (SVS - N_TOK), j = N_TOK + e % (SVS - N_TOK);
        sVT[d * SVS + j] = 0;
    }

    // ---- cfrag = bias + mask - CSHIFT (or -1e30 for pad cols); loads issued
    //      before the barrier so latency hides under staging drain ----
    f32x4 cfrag[7];
    #pragma unroll
    for (int nt = 0; nt < 7; ++nt) {
        int j = nt * 16 + c;
        #pragma unroll
        for (int r = 0; r < 4; ++r) {
            int i = m0 + q * 4 + r;
            float cf;
            if (j < N_TOK) {
                cf = biasD[(h * MT + i) * MT + j] - CSHIFT;
                if (i < N_TOK)
                    cf += mask[((size_t)w * N_TOK + i) * N_TOK + j];
            } else cf = -1e30f;
            cfrag[nt][r] = cf;
        }
    }
    __syncthreads();   // staging done

    // ---- S = Q K^T + (bias+mask-8) : 7 MFMAs with C-in ----
    short8 afrag = *(const short8*)&sQ[(m0 + c) * SQK + q * 8];
    f32x4 acc[7];
    #pragma unroll
    for (int nt = 0; nt < 7; ++nt) {
        short8 bfrag = *(const short8*)&sK[(nt * 16 + c) * SQK + q * 8];
        acc[nt] = __builtin_amdgcn_mfma_f32_16x16x32_bf16(afrag, bfrag, cfrag[nt], 0, 0, 0);
    }
    __syncthreads();   // all QK reads done; sP may overwrite sQ/sK

    // ---- bare expf softmax, write P immediately ----
    float sm[4] = {0.f, 0.f, 0.f, 0.f};
    #pragma unroll
    for (int nt = 0; nt < 7; ++nt) {
        int j = nt * 16 + c;
        #pragma unroll
        for (int r = 0; r < 4; ++r) {
            int i = m0 + q * 4 + r;
            float e = __expf(acc[nt][r]);
            sm[r] += e;
            sP[i * SPS + j] = f2bf(e);
        }
    }
    #pragma unroll
    for (int kk = 0; kk < 4; ++kk)       // zero k-pad cols 112..127 of own rows
        sP[(m0 + c) * SPS + 112 + q * 4 + kk] = 0;
    float inv[4];
    #pragma unroll
    for (int r = 0; r < 4; ++r) {
        float s = sm[r];
        s += __shfl_xor(s, 1);
        s += __shfl_xor(s, 2);
        s += __shfl_xor(s, 4);
        s += __shfl_xor(s, 8);
        inv[r] = 1.0f / s;
    }

    // ---- O = P V : 4 K-tiles x 2 N-tiles (own rows only) ----
    f32x4 oacc[2] = {{0.f,0.f,0.f,0.f}, {0.f,0.f,0.f,0.f}};
    #pragma unroll
    for (int kt = 0; kt < 4; ++kt) {
        short8 pa = *(const short8*)&sP[(m0 + c) * SPS + kt * 32 + q * 8];
        #pragma unroll
        for (int n2 = 0; n2 < 2; ++n2) {
            short8 vb = *(const short8*)&sVT[(n2 * 16 + c) * SVS + kt * 32 + q * 8];
            oacc[n2] = __builtin_amdgcn_mfma_f32_16x16x32_bf16(pa, vb, oacc[n2], 0, 0, 0);
        }
    }

    // ---- epilogue ----
    if (use_bf) {
        #pragma unroll
        for (int n2 = 0; n2 < 2; ++n2)
            #pragma unroll
            for (int r = 0; r < 4; ++r) {
                int i = m0 + q * 4 + r;
                if (i < N_TOK)
                    obf[((size_t)b * N_TOK + i) * DIM + h * HD + n2 * 16 + c]
                        = f2bf(oacc[n2][r] * inv[r]);
            }
    } else {
        #pragma unroll
        for (int n2 = 0; n2 < 2; ++n2)
            #pragma unroll
            for (int r = 0; r < 4; ++r) {
                int i = m0 + q * 4 + r;
                if (i < N_TOK)
                    out[((size_t)b * N_TOK + i) * DIM + h * HD + n2 * 16 + c]
                        = oacc[n2][r] * inv[r];
            }
    }
}

// ---------------------------------------------------------------------------
// Projection, bf16-O path: zero LDS. A-frags direct from global bf16 O;
// W fragments from wperm (L2-hot). out = O @ W^T + b.
// ---------------------------------------------------------------------------
#define PR 112
__global__ __launch_bounds__(448) void proj_bf(
    const short* __restrict__ obf, const short* __restrict__ wperm,
    const float* __restrict__ pbias, float* __restrict__ out)
{
    const int t = threadIdx.x;
    const int lane = t & 63;
    const int c = lane & 15, q = lane >> 4;
    const int m0 = (t >> 6) * 16;
    const size_t r0 = (size_t)blockIdx.x * PR;

    f32x4 acc[8];
    #pragma unroll
    for (int nt = 0; nt < 8; ++nt) acc[nt] = (f32x4){0.f, 0.f, 0.f, 0.f};

    #pragma unroll
    for (int kt = 0; kt < 4; ++kt) {
        short8 a = *(const short8*)&obf[(r0 + m0 + c) * DIM + kt * 32 + q * 8];
        #pragma unroll
        for (int nt = 0; nt < 8; ++nt) {
            short8 wb = *(const short8*)&wperm[(((kt * 8 + nt) * 4 + q) * 16 + c) * 8];
            acc[nt] = __builtin_amdgcn_mfma_f32_16x16x32_bf16(a, wb, acc[nt], 0, 0, 0);
        }
    }
    #pragma unroll
    for (int nt = 0; nt < 8; ++nt) {
        float bc = pbias[nt * 16 + c];
        #pragma unroll
        for (int r = 0; r < 4; ++r)
            out[(r0 + m0 + q * 4 + r) * DIM + nt * 16 + c] = acc[nt][r] + bc;
    }
}

// ---------------------------------------------------------------------------
// Projection fallback (fp32 O in-place in d_out) — verified R0 code.
// ---------------------------------------------------------------------------
__global__ __launch_bounds__(448) void proj_f32(
    const float* __restrict__ wmat, const float* __restrict__ bias,
    float* __restrict__ io)
{
    __shared__ short sX[PR][136];
    __shared__ short sW[DIM][136];
    const int t = threadIdx.x;
    const size_t r0 = (size_t)blockIdx.x * PR;

    for (int e = t; e < PR * 32; e += 448) {
        int rr = e >> 5, k4 = (e & 31) << 2;
        float4 v = *(const float4*)&io[(r0 + rr) * DIM + k4];
        sX[rr][k4 + 0] = f2bf(v.x);
        sX[rr][k4 + 1] = f2bf(v.y);
        sX[rr][k4 + 2] = f2bf(v.z);
        sX[rr][k4 + 3] = f2bf(v.w);
    }
    for (int e = t; e < DIM * 32; e += 448) {
        int rr = e >> 5, k4 = (e & 31) << 2;
        float4 v = *(const float4*)&wmat[rr * DIM + k4];
        sW[rr][k4 + 0] = f2bf(v.x);
        sW[rr][k4 + 1] = f2bf(v.y);
        sW[rr][k4 + 2] = f2bf(v.z);
        sW[rr][k4 + 3] = f2bf(v.w);
    }
    __syncthreads();

    const int lane = t & 63;
    const int c = lane & 15, q = lane >> 4;
    const int mt = t >> 6;

    float bcol[8];
    #pragma unroll
    for (int nt = 0; nt < 8; ++nt) bcol[nt] = bias[nt * 16 + c];

    f32x4 acc[8];
    #pragma unroll
    for (int nt = 0; nt < 8; ++nt) acc[nt] = (f32x4){0.f, 0.f, 0.f, 0.f};

    #pragma unroll
    for (int kt = 0; kt < 4; ++kt) {
        short8 a = *(const short8*)&sX[mt * 16 + c][kt * 32 + q * 8];
        #pragma unroll
        for (int nt = 0; nt < 8; ++nt) {
            short8 bb = *(const short8*)&sW[nt * 16 + c][kt * 32 + q * 8];
            acc[nt] = __builtin_amdgcn_mfma_f32_16x16x32_bf16(a, bb, acc[nt], 0, 0, 0);
        }
    }
    #pragma unroll
    for (int nt = 0; nt < 8; ++nt)
        #pragma unroll
        for (int r = 0; r < 4; ++r)
            io[(r0 + mt * 16 + q * 4 + r) * DIM + nt * 16 + c] = acc[nt][r] + bcol[nt];
}

extern "C" void kernel_launch(void* const* d_in, const int* in_sizes, int n_in,
                              void* d_out, int out_size, void* d_ws, size_t ws_size,
                              hipStream_t stream) {
    const float* x    = (const float*)d_in[0];
    const int*   rpi  = (const int*)  d_in[1];
    const float* mask = (const float*)d_in[2];
    const float* rpb  = (const float*)d_in[3];
    const float* pw   = (const float*)d_in[4];
    const float* pb   = (const float*)d_in[5];
    float* out   = (float*)d_out;
    float* biasD = (float*)d_ws;                           // 200704 B
    short* wperm = (short*)((char*)d_ws + WPERM_BYTE_OFF); // 32768 B
    short* obf   = (short*)((char*)d_ws + OBF_BYTE_OFF);   // 51.4 MB (if room)

    const int use_bf = (ws_size >= OBF_BYTE_OFF + OBF_BYTES) ? 1 : 0;

    prep_kernel<<<(BIAS_ELEMS + WPERM_ELEMS + 255) / 256, 256, 0, stream>>>(
        rpi, rpb, pw, biasD, wperm);
    attn_kernel<<<B_TOT * NH, 448, 0, stream>>>(x, mask, biasD, out, obf, use_bf);
    if (use_bf)
        proj_bf<<<(B_TOT * N_TOK) / PR, 448, 0, stream>>>(obf, wperm, pb, out);
    else
        proj_f32<<<(B_TOT * N_TOK) / PR, 448, 0, stream>>>(pw, pb, out);
}

// Round 5
// 542.081 us; speedup vs baseline: 1.5638x; 1.1207x over previous
//
#include <hip/hip_runtime.h>

typedef __attribute__((ext_vector_type(8))) short short8;
typedef __attribute__((ext_vector_type(4))) float f32x4;

#define N_TOK 98
#define HD    32
#define NH    4
#define DIM   128
#define C3    384
#define NWIN  64
#define B_TOT 2048
#define MT    112                    // padded token count (7 x 16)
#define SCALE 0.17677669529663687f   // 1/sqrt(32)
#define CSHIFT 8.0f                  // uniform softmax shift (cancels in normalization)

// attn LDS layout (bytes):
//   sQ [112][40]s @0 (8960), sK [112][40]s @8960 (8960)
//   sP [112][136]s @0 (30464) -- aliases sQ/sK after QK barrier
//   sVT [32][136]s @30464 (8704)
#define SQK    40
#define SPS    136
#define SVS    136
#define K_OFF  8960
#define VT_OFF 30464
#define LDSZ   39168

// workspace layout
#define WPERM_ELEMS (NH * 8 * 4 * 16 * 8)    // 16384 shorts = 32768 B @ 0
#define BIAS_OFF    32768
#define BIAS_ELEMS  (NH * MT * MT)           // 50176 fp32 = 200704 B
#define CMB_OFF     233472
#define CMB_ELEMS   (NWIN * NH * 7 * 7 * 64 * 4)   // 3,211,264 fp32 = 12,845,056 B
#define OBF_FULL_OFF 13078528
#define OBF_BYTES   ((size_t)B_TOT * N_TOK * DIM * 2)   // 51,380,224
#define FULL_BYTES  (OBF_FULL_OFF + OBF_BYTES)          // 64,458,752
#define OBF_FB_OFF  233472                               // fallback: obf after biasD

__device__ __forceinline__ short f2bf(float f) {       // RNE fp32->bf16
    unsigned u = __builtin_bit_cast(unsigned, f);
    u += 0x7fffu + ((u >> 16) & 1u);
    return (short)(u >> 16);
}

// ---------------------------------------------------------------------------
// prep: wperm (fragment-ordered bf16 W), biasD (dense fallback), and
//       cmb fragment-ordered fp32 (bias+mask-CSHIFT), layout:
//       cmb[(((w*4+h)*7+mt)*7+nt)*256 + lane*4 + r]
//         = bias(h,i,j)+mask(w,i,j)-8   (i=mt*16+(lane>>4)*4+r, j=nt*16+(lane&15))
//         or -1e30 if i>=98 or j>=98
// ---------------------------------------------------------------------------
__global__ void prep_kernel(const int* __restrict__ rpi,
                            const float* __restrict__ rpb,
                            const float* __restrict__ wmat,
                            const float* __restrict__ mask,
                            short* __restrict__ wperm,
                            float* __restrict__ biasD,
                            float* __restrict__ cmb, const int do_cmb) {
    int idx = blockIdx.x * 256 + threadIdx.x;
    if (idx < WPERM_ELEMS) {
        int e = idx;
        int k = e & 7, r2 = e >> 3;
        int c = r2 & 15; r2 >>= 4;
        int q = r2 & 3;  r2 >>= 2;
        int nt = r2 & 7; int h = r2 >> 3;
        wperm[e] = f2bf(wmat[(nt * 16 + c) * DIM + h * HD + q * 8 + k]);
    } else if (idx < WPERM_ELEMS + BIAS_ELEMS) {
        int e = idx - WPERM_ELEMS;
        int j = e % MT, rest = e / MT;
        int i = rest % MT, h = rest / MT;
        float v = 0.f;
        if (i < N_TOK && j < N_TOK) v = rpb[rpi[i * N_TOK + j] * NH + h];
        biasD[e] = v;
    } else if (do_cmb) {
        int e = idx - (WPERM_ELEMS + BIAS_ELEMS);
        if (e < CMB_ELEMS) {
            int r = e & 3, ln = (e >> 2) & 63;
            int g = e >> 8;
            int nt = g % 7; g /= 7;
            int mt = g % 7; g /= 7;
            int h = g & 3, ww = g >> 2;
            int i = mt * 16 + (ln >> 4) * 4 + r;
            int j = nt * 16 + (ln & 15);
            float v = -1e30f;
            if (i < N_TOK && j < N_TOK)
                v = rpb[rpi[i * N_TOK + j] * NH + h]
                  + mask[((size_t)ww * N_TOK + i) * N_TOK + j] - CSHIFT;
            cmb[e] = v;
        }
    }
}

// ---------------------------------------------------------------------------
// Pipelined attention: 1 block per window, loops 4 heads; next head's
// global loads held in registers across current head's compute (issue-early
// write-late). 448 thr = 7 waves = 7 M-tiles. One problem = R4's verified body.
// ---------------------------------------------------------------------------
__global__ __launch_bounds__(448, 6) void attn_pipe(
    const float* __restrict__ x, const float* __restrict__ cmb,
    short* __restrict__ obf)
{
    __shared__ __align__(16) char smem[LDSZ];
    short* sQ  = (short*)smem;                 // [112][40]
    short* sK  = (short*)(smem + K_OFF);       // [112][40]
    short* sP  = (short*)smem;                 // [112][136], aliases sQ/sK
    short* sVT = (short*)(smem + VT_OFF);      // [32][136]

    const int t = threadIdx.x;
    const int b = blockIdx.x;
    const int w = b & (NWIN - 1);
    const float* xb = x + (size_t)b * N_TOK * C3;

    const int lane  = t & 63;
    const int c     = lane & 15, q = lane >> 4;
    const int mtile = t >> 6;
    const int m0    = mtile * 16;

    // staging task decode (matches R4's strided loops, unrolled 2x)
    const int row0 = t >> 3, d40 = (t & 7) << 2;   // Q/K elem 0: rows 0..55
    const int row1 = row0 + 56;                    // Q/K elem 1: rows 56..111
    const bool r1ok = row1 < N_TOK;
    const int vj0 = row0, vd0 = d40;               // V elem 0: tokens 0..55
    const int vj1 = vj0 + 56;                      // V elem 1: tokens 56..111
    const bool v1ok = vj1 < N_TOK;

    float4 qv0 = {0,0,0,0}, kv0 = {0,0,0,0};
    float4 qv1 = {0,0,0,0}, kv1 = {0,0,0,0};
    float4 vv0 = {0,0,0,0}, vv1 = {0,0,0,0};

    // ---- prologue: issue head-0 loads; zero sVT token-pad cols ----
    {
        const float* base = xb;                    // h = 0
        const float* p0 = base + row0 * C3 + d40;
        qv0 = *(const float4*)p0;
        kv0 = *(const float4*)(p0 + DIM);
        if (r1ok) {
            const float* p1 = base + row1 * C3 + d40;
            qv1 = *(const float4*)p1;
            kv1 = *(const float4*)(p1 + DIM);
        }
        vv0 = *(const float4*)(base + vj0 * C3 + 2 * DIM + vd0);
        if (v1ok) vv1 = *(const float4*)(base + vj1 * C3 + 2 * DIM + vd0);
    }
    for (int e = t; e < HD * (SVS - N_TOK); e += 448) {
        int d = e / (SVS - N_TOK), j = N_TOK + e % (SVS - N_TOK);
        sVT[d * SVS + j] = 0;
    }

    #pragma unroll 1
    for (int h = 0; h < NH; ++h) {
        __syncthreads();   // A: prior head's sP/sVT reads done; restage safe

        // ---- write stage from held registers (vmcnt drained at barrier A) ----
        {
            unsigned long long qp0 =
                  (unsigned long long)(unsigned short)f2bf(qv0.x * SCALE)
               | ((unsigned long long)(unsigned short)f2bf(qv0.y * SCALE) << 16)
               | ((unsigned long long)(unsigned short)f2bf(qv0.z * SCALE) << 32)
               | ((unsigned long long)(unsigned short)f2bf(qv0.w * SCALE) << 48);
            unsigned long long kp0 =
                  (unsigned long long)(unsigned short)f2bf(kv0.x)
               | ((unsigned long long)(unsigned short)f2bf(kv0.y) << 16)
               | ((unsigned long long)(unsigned short)f2bf(kv0.z) << 32)
               | ((unsigned long long)(unsigned short)f2bf(kv0.w) << 48);
            *(unsigned long long*)&sQ[row0 * SQK + d40] = qp0;
            *(unsigned long long*)&sK[row0 * SQK + d40] = kp0;
            unsigned long long qp1 = 0ull, kp1 = 0ull;
            if (r1ok) {
                qp1 =  (unsigned long long)(unsigned short)f2bf(qv1.x * SCALE)
                   | ((unsigned long long)(unsigned short)f2bf(qv1.y * SCALE) << 16)
                   | ((unsigned long long)(unsigned short)f2bf(qv1.z * SCALE) << 32)
                   | ((unsigned long long)(unsigned short)f2bf(qv1.w * SCALE) << 48);
                kp1 =  (unsigned long long)(unsigned short)f2bf(kv1.x)
                   | ((unsigned long long)(unsigned short)f2bf(kv1.y) << 16)
                   | ((unsigned long long)(unsigned short)f2bf(kv1.z) << 32)
                   | ((unsigned long long)(unsigned short)f2bf(kv1.w) << 48);
            }
            *(unsigned long long*)&sQ[row1 * SQK + d40] = qp1;
            *(unsigned long long*)&sK[row1 * SQK + d40] = kp1;
            sVT[(vd0 + 0) * SVS + vj0] = f2bf(vv0.x);
            sVT[(vd0 + 1) * SVS + vj0] = f2bf(vv0.y);
            sVT[(vd0 + 2) * SVS + vj0] = f2bf(vv0.z);
            sVT[(vd0 + 3) * SVS + vj0] = f2bf(vv0.w);
            if (v1ok) {
                sVT[(vd0 + 0) * SVS + vj1] = f2bf(vv1.x);
                sVT[(vd0 + 1) * SVS + vj1] = f2bf(vv1.y);
                sVT[(vd0 + 2) * SVS + vj1] = f2bf(vv1.z);
                sVT[(vd0 + 3) * SVS + vj1] = f2bf(vv1.w);
            }
        }

        // ---- cfrag: 7 coalesced float4 from fragment-ordered cmb (L2-hot) ----
        const float* cb = cmb
            + ((size_t)((w * NH + h) * 7 + mtile) * 7) * 256 + lane * 4;
        f32x4 cf[7];
        #pragma unroll
        for (int nt = 0; nt < 7; ++nt)
            cf[nt] = *(const f32x4*)(cb + nt * 256);

        __syncthreads();   // B: staging visible

        // ---- S = Q K^T + (bias+mask-8) : 7 MFMAs with C-in ----
        short8 afrag = *(const short8*)&sQ[(m0 + c) * SQK + q * 8];
        f32x4 acc[7];
        #pragma unroll
        for (int nt = 0; nt < 7; ++nt) {
            short8 bfrag = *(const short8*)&sK[(nt * 16 + c) * SQK + q * 8];
            acc[nt] = __builtin_amdgcn_mfma_f32_16x16x32_bf16(afrag, bfrag, cf[nt], 0, 0, 0);
        }
        __syncthreads();   // C: QK ds-reads done; sP may overwrite sQ/sK

        // ---- prefetch next head's loads (consumed at next loop-top) ----
        if (h + 1 < NH) {
            const float* base = xb + (h + 1) * HD;
            const float* p0 = base + row0 * C3 + d40;
            qv0 = *(const float4*)p0;
            kv0 = *(const float4*)(p0 + DIM);
            if (r1ok) {
                const float* p1 = base + row1 * C3 + d40;
                qv1 = *(const float4*)p1;
                kv1 = *(const float4*)(p1 + DIM);
            }
            vv0 = *(const float4*)(base + vj0 * C3 + 2 * DIM + vd0);
            if (v1ok) vv1 = *(const float4*)(base + vj1 * C3 + 2 * DIM + vd0);
        }

        // ---- bare expf softmax, write P immediately ----
        float sm[4] = {0.f, 0.f, 0.f, 0.f};
        #pragma unroll
        for (int nt = 0; nt < 7; ++nt) {
            int j = nt * 16 + c;
            #pragma unroll
            for (int r = 0; r < 4; ++r) {
                int i = m0 + q * 4 + r;
                float e = __expf(acc[nt][r]);
                sm[r] += e;
                sP[i * SPS + j] = f2bf(e);
            }
        }
        #pragma unroll
        for (int kk = 0; kk < 4; ++kk)   // zero k-pad cols 112..127 of own rows
            sP[(m0 + c) * SPS + 112 + q * 4 + kk] = 0;
        float inv[4];
        #pragma unroll
        for (int r = 0; r < 4; ++r) {
            float s = sm[r];
            s += __shfl_xor(s, 1);
            s += __shfl_xor(s, 2);
            s += __shfl_xor(s, 4);
            s += __shfl_xor(s, 8);
            inv[r] = 1.0f / s;
        }

        // ---- O = P V : 4 K-tiles x 2 N-tiles (own rows only) ----
        f32x4 oacc[2] = {{0.f,0.f,0.f,0.f}, {0.f,0.f,0.f,0.f}};
        #pragma unroll
        for (int kt = 0; kt < 4; ++kt) {
            short8 pa = *(const short8*)&sP[(m0 + c) * SPS + kt * 32 + q * 8];
            #pragma unroll
            for (int n2 = 0; n2 < 2; ++n2) {
                short8 vb = *(const short8*)&sVT[(n2 * 16 + c) * SVS + kt * 32 + q * 8];
                oacc[n2] = __builtin_amdgcn_mfma_f32_16x16x32_bf16(pa, vb, oacc[n2], 0, 0, 0);
            }
        }
        // ---- epilogue: bf16 O ----
        #pragma unroll
        for (int n2 = 0; n2 < 2; ++n2)
            #pragma unroll
            for (int r = 0; r < 4; ++r) {
                int i = m0 + q * 4 + r;
                if (i < N_TOK)
                    obf[((size_t)b * N_TOK + i) * DIM + h * HD + n2 * 16 + c]
                        = f2bf(oacc[n2][r] * inv[r]);
            }
    }
}

// ---------------------------------------------------------------------------
// R4-verified fallback attention (used when ws too small for cmb+obf).
// ---------------------------------------------------------------------------
__global__ __launch_bounds__(448, 7) void attn_fb(
    const float* __restrict__ x, const float* __restrict__ mask,
    const float* __restrict__ biasD, float* __restrict__ out,
    short* __restrict__ obf, const int use_bf)
{
    __shared__ __align__(16) char smem[LDSZ];
    short* sQ  = (short*)smem;
    short* sK  = (short*)(smem + K_OFF);
    short* sP  = (short*)smem;
    short* sVT = (short*)(smem + VT_OFF);

    const int t  = threadIdx.x;
    const int bh = blockIdx.x;
    const int b  = bh >> 2, h = bh & 3;
    const int w  = b & (NWIN - 1);
    const float* xb = x + (size_t)b * N_TOK * C3;

    const int lane = t & 63;
    const int c    = lane & 15, q = lane >> 4;
    const int m0   = (t >> 6) * 16;

    for (int e = t; e < MT * 8; e += 448) {
        int row = e >> 3, d4 = (e & 7) << 2;
        unsigned long long qp = 0ull, kp = 0ull;
        if (row < N_TOK) {
            const float* p = xb + row * C3 + h * HD + d4;
            float4 qv = *(const float4*)p;
            float4 kv = *(const float4*)(p + DIM);
            qp =  (unsigned long long)(unsigned short)f2bf(qv.x * SCALE)
               | ((unsigned long long)(unsigned short)f2bf(qv.y * SCALE) << 16)
               | ((unsigned long long)(unsigned short)f2bf(qv.z * SCALE) << 32)
               | ((unsigned long long)(unsigned short)f2bf(qv.w * SCALE) << 48);
            kp =  (unsigned long long)(unsigned short)f2bf(kv.x)
               | ((unsigned long long)(unsigned short)f2bf(kv.y) << 16)
               | ((unsigned long long)(unsigned short)f2bf(kv.z) << 32)
               | ((unsigned long long)(unsigned short)f2bf(kv.w) << 48);
        }
        *(unsigned long long*)&sQ[row * SQK + d4] = qp;
        *(unsigned long long*)&sK[row * SQK + d4] = kp;
    }
    for (int e = t; e < N_TOK * 8; e += 448) {
        int j = e >> 3, d4 = (e & 7) << 2;
        float4 vv = *(const float4*)(xb + j * C3 + 2 * DIM + h * HD + d4);
        sVT[(d4 + 0) * SVS + j] = f2bf(vv.x);
        sVT[(d4 + 1) * SVS + j] = f2bf(vv.y);
        sVT[(d4 + 2) * SVS + j] = f2bf(vv.z);
        sVT[(d4 + 3) * SVS + j] = f2bf(vv.w);
    }
    for (int e = t; e < HD * (SVS - N_TOK); e += 448) {
        int d = e / (SVS - N_TOK), j = N_TOK + e % (SVS - N_TOK);
        sVT[d * SVS + j] = 0;
    }

    f32x4 cfrag[7];
    #pragma unroll
    for (int nt = 0; nt < 7; ++nt) {
        int j = nt * 16 + c;
        #pragma unroll
        for (int r = 0; r < 4; ++r) {
            int i = m0 + q * 4 + r;
            float cf;
            if (j < N_TOK) {
                cf = biasD[(h * MT + i) * MT + j] - CSHIFT;
                if (i < N_TOK)
                    cf += mask[((size_t)w * N_TOK + i) * N_TOK + j];
            } else cf = -1e30f;
            cfrag[nt][r] = cf;
        }
    }
    __syncthreads();

    short8 afrag = *(const short8*)&sQ[(m0 + c) * SQK + q * 8];
    f32x4 acc[7];
    #pragma unroll
    for (int nt = 0; nt < 7; ++nt) {
        short8 bfrag = *(const short8*)&sK[(nt * 16 + c) * SQK + q * 8];
        acc[nt] = __builtin_amdgcn_mfma_f32_16x16x32_bf16(afrag, bfrag, cfrag[nt], 0, 0, 0);
    }
    __syncthreads();

    float sm[4] = {0.f, 0.f, 0.f, 0.f};
    #pragma unroll
    for (int nt = 0; nt < 7; ++nt) {
        int j = nt * 16 + c;
        #pragma unroll
        for (int r = 0; r < 4; ++r) {
            int i = m0 + q * 4 + r;
            float e = __expf(acc[nt][r]);
            sm[r] += e;
            sP[i * SPS + j] = f2bf(e);
        }
    }
    #pragma unroll
    for (int kk = 0; kk < 4; ++kk)
        sP[(m0 + c) * SPS + 112 + q * 4 + kk] = 0;
    float inv[4];
    #pragma unroll
    for (int r = 0; r < 4; ++r) {
        float s = sm[r];
        s += __shfl_xor(s, 1);
        s += __shfl_xor(s, 2);
        s += __shfl_xor(s, 4);
        s += __shfl_xor(s, 8);
        inv[r] = 1.0f / s;
    }

    f32x4 oacc[2] = {{0.f,0.f,0.f,0.f}, {0.f,0.f,0.f,0.f}};
    #pragma unroll
    for (int kt = 0; kt < 4; ++kt) {
        short8 pa = *(const short8*)&sP[(m0 + c) * SPS + kt * 32 + q * 8];
        #pragma unroll
        for (int n2 = 0; n2 < 2; ++n2) {
            short8 vb = *(const short8*)&sVT[(n2 * 16 + c) * SVS + kt * 32 + q * 8];
            oacc[n2] = __builtin_amdgcn_mfma_f32_16x16x32_bf16(pa, vb, oacc[n2], 0, 0, 0);
        }
    }
    if (use_bf) {
        #pragma unroll
        for (int n2 = 0; n2 < 2; ++n2)
            #pragma unroll
            for (int r = 0; r < 4; ++r) {
                int i = m0 + q * 4 + r;
                if (i < N_TOK)
                    obf[((size_t)b * N_TOK + i) * DIM + h * HD + n2 * 16 + c]
                        = f2bf(oacc[n2][r] * inv[r]);
            }
    } else {
        #pragma unroll
        for (int n2 = 0; n2 < 2; ++n2)
            #pragma unroll
            for (int r = 0; r < 4; ++r) {
                int i = m0 + q * 4 + r;
                if (i < N_TOK)
                    out[((size_t)b * N_TOK + i) * DIM + h * HD + n2 * 16 + c]
                        = oacc[n2][r] * inv[r];
            }
    }
}

// ---------------------------------------------------------------------------
// Projection, bf16-O path: zero LDS. A-frags direct from global bf16 O;
// W fragments from wperm (L2-hot). out = O @ W^T + b.
// ---------------------------------------------------------------------------
#define PR 112
__global__ __launch_bounds__(448) void proj_bf(
    const short* __restrict__ obf, const short* __restrict__ wperm,
    const float* __restrict__ pbias, float* __restrict__ out)
{
    const int t = threadIdx.x;
    const int lane = t & 63;
    const int c = lane & 15, q = lane >> 4;
    const int m0 = (t >> 6) * 16;
    const size_t r0 = (size_t)blockIdx.x * PR;

    f32x4 acc[8];
    #pragma unroll
    for (int nt = 0; nt < 8; ++nt) acc[nt] = (f32x4){0.f, 0.f, 0.f, 0.f};

    #pragma unroll
    for (int kt = 0; kt < 4; ++kt) {
        short8 a = *(const short8*)&obf[(r0 + m0 + c) * DIM + kt * 32 + q * 8];
        #pragma unroll
        for (int nt = 0; nt < 8; ++nt) {
            short8 wb = *(const short8*)&wperm[(((kt * 8 + nt) * 4 + q) * 16 + c) * 8];
            acc[nt] = __builtin_amdgcn_mfma_f32_16x16x32_bf16(a, wb, acc[nt], 0, 0, 0);
        }
    }
    #pragma unroll
    for (int nt = 0; nt < 8; ++nt) {
        float bc = pbias[nt * 16 + c];
        #pragma unroll
        for (int r = 0; r < 4; ++r)
            out[(r0 + m0 + q * 4 + r) * DIM + nt * 16 + c] = acc[nt][r] + bc;
    }
}

// ---------------------------------------------------------------------------
// Projection fallback (fp32 O in-place in d_out) — verified R0 code.
// ---------------------------------------------------------------------------
__global__ __launch_bounds__(448) void proj_f32(
    const float* __restrict__ wmat, const float* __restrict__ bias,
    float* __restrict__ io)
{
    __shared__ short sX[PR][136];
    __shared__ short sW[DIM][136];
    const int t = threadIdx.x;
    const size_t r0 = (size_t)blockIdx.x * PR;

    for (int e = t; e < PR * 32; e += 448) {
        int rr = e >> 5, k4 = (e & 31) << 2;
        float4 v = *(const float4*)&io[(r0 + rr) * DIM + k4];
        sX[rr][k4 + 0] = f2bf(v.x);
        sX[rr][k4 + 1] = f2bf(v.y);
        sX[rr][k4 + 2] = f2bf(v.z);
        sX[rr][k4 + 3] = f2bf(v.w);
    }
    for (int e = t; e < DIM * 32; e += 448) {
        int rr = e >> 5, k4 = (e & 31) << 2;
        float4 v = *(const float4*)&wmat[rr * DIM + k4];
        sW[rr][k4 + 0] = f2bf(v.x);
        sW[rr][k4 + 1] = f2bf(v.y);
        sW[rr][k4 + 2] = f2bf(v.z);
        sW[rr][k4 + 3] = f2bf(v.w);
    }
    __syncthreads();

    const int lane = t & 63;
    const int c = lane & 15, q = lane >> 4;
    const int mt = t >> 6;

    float bcol[8];
    #pragma unroll
    for (int nt = 0; nt < 8; ++nt) bcol[nt] = bias[nt * 16 + c];

    f32x4 acc[8];
    #pragma unroll
    for (int nt = 0; nt < 8; ++nt) acc[nt] = (f32x4){0.f, 0.f, 0.f, 0.f};

    #pragma unroll
    for (int kt = 0; kt < 4; ++kt) {
        short8 a = *(const short8*)&sX[mt * 16 + c][kt * 32 + q * 8];
        #pragma unroll
        for (int nt = 0; nt < 8; ++nt) {
            short8 bb = *(const short8*)&sW[nt * 16 + c][kt * 32 + q * 8];
            acc[nt] = __builtin_amdgcn_mfma_f32_16x16x32_bf16(a, bb, acc[nt], 0, 0, 0);
        }
    }
    #pragma unroll
    for (int nt = 0; nt < 8; ++nt)
        #pragma unroll
        for (int r = 0; r < 4; ++r)
            io[(r0 + mt * 16 + q * 4 + r) * DIM + nt * 16 + c] = acc[nt][r] + bcol[nt];
}

extern "C" void kernel_launch(void* const* d_in, const int* in_sizes, int n_in,
                              void* d_out, int out_size, void* d_ws, size_t ws_size,
                              hipStream_t stream) {
    const float* x    = (const float*)d_in[0];
    const int*   rpi  = (const int*)  d_in[1];
    const float* mask = (const float*)d_in[2];
    const float* rpb  = (const float*)d_in[3];
    const float* pw   = (const float*)d_in[4];
    const float* pb   = (const float*)d_in[5];
    float* out   = (float*)d_out;
    short* wperm = (short*)d_ws;
    float* biasD = (float*)((char*)d_ws + BIAS_OFF);
    float* cmb   = (float*)((char*)d_ws + CMB_OFF);

    const int full = (ws_size >= FULL_BYTES) ? 1 : 0;
    short* obf = (short*)((char*)d_ws + (full ? OBF_FULL_OFF : OBF_FB_OFF));
    const int fb_bf = (ws_size >= OBF_FB_OFF + OBF_BYTES) ? 1 : 0;

    const int prep_elems = WPERM_ELEMS + BIAS_ELEMS + (full ? CMB_ELEMS : 0);
    prep_kernel<<<(prep_elems + 255) / 256, 256, 0, stream>>>(
        rpi, rpb, pw, mask, wperm, biasD, cmb, full);

    if (full) {
        attn_pipe<<<B_TOT, 448, 0, stream>>>(x, cmb, obf);
        proj_bf<<<(B_TOT * N_TOK) / PR, 448, 0, stream>>>(obf, wperm, pb, out);
    } else {
        attn_fb<<<B_TOT * NH, 448, 0, stream>>>(x, mask, biasD, out, obf, fb_bf);
        if (fb_bf)
            proj_bf<<<(B_TOT * N_TOK) / PR, 448, 0, stream>>>(obf, wperm, pb, out);
        else
            proj_f32<<<(B_TOT * N_TOK) / PR, 448, 0, stream>>>(pw, pb, out);
    }
}